// Round 6
// baseline (669.966 us; speedup 1.0000x reference)
//
#include <hip/hip_runtime.h>
#include <cstdint>

// RingAttractorNetwork: B=2048, N_EXC=1024, N_INH=256, 10 steps.
// Round 6: (1) Poisson noise offloaded to co-scheduled blocks in the same
// dispatch (dispatch t computes step-t+1 k-counts; epilogue just reads u8) —
// noise depends only on (step, idx), never on state. (2) 3-buffer counted-vmcnt
// pipeline: "s_waitcnt vmcnt(4); s_barrier" instead of __syncthreads so
// prefetch loads stay in flight across 2 tiles (T4).
// RNG replays JAX threefry with jax_threefry_partitionable=True (verified r2).

#define N_EXC 1024
#define N_INH 256
#define BATCH 2048
#define STEPS 10
#define MAX_POIS 32
#define NE_TOT (BATCH * N_EXC)            // 2,097,152
#define NTOT   (NE_TOT + BATCH * N_INH)   // 2,621,440
#define NZ_SLICES 8                        // noise y-slices in step dispatch

typedef short s16x8 __attribute__((ext_vector_type(8)));
typedef float f32x4 __attribute__((ext_vector_type(4)));

typedef __attribute__((address_space(1))) const void GV;
typedef __attribute__((address_space(3))) void LV;

struct U2 { uint32_t x, y; };

__device__ __forceinline__ uint32_t rotl32(uint32_t v, int r) {
  return (v << r) | (v >> (32 - r));
}

// JAX threefry2x32 (20 rounds).
__device__ __forceinline__ U2 threefry(U2 k, uint32_t x0, uint32_t x1) {
  uint32_t ks0 = k.x, ks1 = k.y, ks2 = k.x ^ k.y ^ 0x1BD11BDAu;
  x0 += ks0; x1 += ks1;
#define TF_R4(a,b,c,d) \
  x0 += x1; x1 = rotl32(x1,a); x1 ^= x0; \
  x0 += x1; x1 = rotl32(x1,b); x1 ^= x0; \
  x0 += x1; x1 = rotl32(x1,c); x1 ^= x0; \
  x0 += x1; x1 = rotl32(x1,d); x1 ^= x0;
  TF_R4(13,15,26,6)  x0 += ks1; x1 += ks2 + 1u;
  TF_R4(17,29,16,24) x0 += ks2; x1 += ks0 + 2u;
  TF_R4(13,15,26,6)  x0 += ks0; x1 += ks1 + 3u;
  TF_R4(17,29,16,24) x0 += ks1; x1 += ks2 + 4u;
  TF_R4(13,15,26,6)  x0 += ks2; x1 += ks0 + 5u;
#undef TF_R4
  U2 r; r.x = x0; r.y = x1; return r;
}

__device__ __forceinline__ unsigned short f2b(float f) {
  uint32_t u = __float_as_uint(f);
  return (unsigned short)((u + 0x7FFFu + ((u >> 16) & 1u)) >> 16);  // RNE
}

__device__ __forceinline__ void gload16(const void* g, void* l) {
  __builtin_amdgcn_global_load_lds((GV*)g, (LV*)l, 16, 0, 0);
}

// Knuth Poisson k-count for flat elements [f0::stride) of both pools.
// Partitionable random_bits: bits = h.x ^ h.y, h = threefry(subkey_n, 0, e).
__device__ void gen_noise(int f0, int stride,
                          const U2* __restrict__ ske, const U2* __restrict__ ski,
                          float lam_e, float lam_i,
                          uint8_t* __restrict__ nze, uint8_t* __restrict__ nzi) {
  for (int f = f0; f < NTOT; f += stride) {
    bool ii = f >= NE_TOT;
    uint32_t e = ii ? (uint32_t)(f - NE_TOT) : (uint32_t)f;
    const U2* sk = ii ? ski : ske;
    float neg = ii ? -lam_i : -lam_e;
    float lp = 0.0f;
    int k = 0;
#pragma unroll 1
    for (int n = 0; n < MAX_POIS; ++n) {
      if (!(lp > neg)) break;
      k++;
      U2 h = threefry(sk[n], 0u, e);
      uint32_t bits = h.x ^ h.y;
      float u = __uint_as_float((bits >> 9) | 0x3f800000u) - 1.0f;
      lp += logf(u);
    }
    (ii ? nzi : nze)[e] = (uint8_t)(k - 1);   // Poisson value, >= 0
  }
}

// Subkey chains: key = fold_in(key(42), t), split -> (ke, ki); iterated
// fold-like splits give the per-while-iteration uniform subkeys.
__global__ void keys_kernel(U2* subk_e, U2* subk_i) {
  int tid = threadIdx.x;
  if (tid >= 2 * STEPS) return;
  int t = tid >> 1;
  bool is_i = tid & 1;
  U2 base; base.x = 0u; base.y = 42u;
  U2 folded = threefry(base, 0u, (uint32_t)t);        // fold_in
  U2 ke = threefry(folded, 0u, 0u);                   // partitionable split
  U2 ki = threefry(folded, 0u, 1u);
  U2 rng = is_i ? ki : ke;
  U2* dst = (is_i ? subk_i : subk_e) + t * MAX_POIS;
  for (int n = 0; n < MAX_POIS; ++n) {
    dst[n] = threefry(rng, 0u, 1u);                   // subkey
    rng = threefry(rng, 0u, 0u);                      // carried rng
  }
}

// Step-0 noise (once, before the loop).
__global__ __launch_bounds__(256) void noise0_kernel(
    const U2* __restrict__ subk_e, const U2* __restrict__ subk_i,
    const float* __restrict__ sc_rate_e, const float* __restrict__ sc_rate_i,
    uint8_t* __restrict__ nze, uint8_t* __restrict__ nzi) {
  int flat = blockIdx.x * 256 + threadIdx.x;
  gen_noise(flat, gridDim.x * 256, subk_e, subk_i, *sc_rate_e, *sc_rate_i, nze, nzi);
}

// W_EE ring weights -> bf16. Row-normalize (incl. diagonal) in f32, then zero diag.
__global__ __launch_bounds__(256) void wee_kernel(const float* __restrict__ sigma_p,
                                                  unsigned short* __restrict__ W) {
  int i = blockIdx.x;
  int tid = threadIdx.x;
  float sigma = *sigma_p;
  const float twopi = 6.28318530717958647692f;
  const float delta = twopi / 1023.0f;
  float ai = (float)i * delta;
  float w[4];
  float s = 0.0f;
#pragma unroll
  for (int q = 0; q < 4; ++q) {
    int j = tid + q * 256;
    float aj = (float)j * delta;
    float d = aj - ai;
    float wd = atan2f(sinf(d), cosf(d));
    float x = wd / sigma;
    float v = expf(-0.5f * x * x);
    w[q] = v;
    s += v;
  }
  __shared__ float red[256];
  red[tid] = s;
  __syncthreads();
  for (int off = 128; off > 0; off >>= 1) {
    if (tid < off) red[tid] += red[tid + off];
    __syncthreads();
  }
  float sum = red[0];
#pragma unroll
  for (int q = 0; q < 4; ++q) {
    int j = tid + q * 256;
    W[i * N_EXC + j] = (j == i) ? (unsigned short)0 : f2b(w[q] / sum);
  }
}

// Transposed/converted weights + h->bf16.
__global__ void setup_kernel(const float* __restrict__ W_EI, const float* __restrict__ W_IE,
                             const float* __restrict__ h,
                             unsigned short* __restrict__ W_EIT,   // [256][1024]
                             unsigned short* __restrict__ W_IET,   // [1024][256]
                             unsigned short* __restrict__ hb) {
  int tid = blockIdx.x * blockDim.x + threadIdx.x;
  int nt = gridDim.x * blockDim.x;
  for (int i = tid; i < BATCH * N_EXC; i += nt) hb[i] = f2b(h[i]);
  for (int i = tid; i < N_INH * N_EXC; i += nt) {
    int r = i >> 10, c = i & 1023;
    W_EIT[i] = f2b(W_EI[c * N_INH + r]);
  }
  for (int i = tid; i < N_EXC * N_INH; i += nt) {
    int r = i >> 8, c = i & 255;
    W_IET[i] = f2b(W_IE[c * N_EXC + r]);
  }
}

// 64x64-tile GEMM phase; 3 LDS buffers; gload_lds staging (XOR-swizzled, rule 21);
// counted-vmcnt pipeline: loads issued post-barrier at iter t drain at iter t+2's
// "vmcnt(4); s_barrier" (one asm => memory ops can't cross). Prefetch target buf
// (t+2)%3 was last read at iter t-1 and all waves passed the iter-t barrier after
// that read, so the overwrite is safe. Final iter waits vmcnt(0); phase exits drained.
#define PIPE_GEMM(APTR, LDA, AROW0, BPTR, LDB, BROW0, KLEN, ACC)                \
  {                                                                             \
    const int NT = (KLEN) / 64;                                                 \
    int c0 = wave * 128 + lane;                                                 \
    int c1 = c0 + 64;                                                           \
    int r0 = c0 >> 3, q0 = ((c0 & 7) ^ (r0 & 7)) << 3;                          \
    int r1 = c1 >> 3, q1 = ((c1 & 7) ^ (r1 & 7)) << 3;                          \
    const unsigned short* ap0 = (APTR) + (size_t)((AROW0) + r0) * (LDA) + q0;   \
    const unsigned short* ap1 = (APTR) + (size_t)((AROW0) + r1) * (LDA) + q1;   \
    const unsigned short* bp0 = (BPTR) + (size_t)((BROW0) + r0) * (LDB) + q0;   \
    const unsigned short* bp1 = (BPTR) + (size_t)((BROW0) + r1) * (LDB) + q1;   \
    char* la0 = (char*)As + wave * 2048;                                        \
    char* la1 = la0 + 1024;                                                     \
    char* lb0 = (char*)Bs + wave * 2048;                                        \
    char* lb1 = lb0 + 1024;                                                     \
    gload16(ap0, la0); gload16(ap1, la1);                                       \
    gload16(bp0, lb0); gload16(bp1, lb1);                                       \
    gload16(ap0 + 64, la0 + 8192); gload16(ap1 + 64, la1 + 8192);               \
    gload16(bp0 + 64, lb0 + 8192); gload16(bp1 + 64, lb1 + 8192);               \
    int rd = 0, wr2 = 16384;                                                    \
    int raf0 = wr * 32 + l16, raf1 = raf0 + 16;                                 \
    int rbf0 = wc * 32 + l16, rbf1 = rbf0 + 16;                                 \
    int aA0 = (raf0 << 7) | ((lhi ^ (raf0 & 7)) << 4);                          \
    int aA1 = (raf1 << 7) | ((lhi ^ (raf1 & 7)) << 4);                          \
    int aB0 = (rbf0 << 7) | ((lhi ^ (rbf0 & 7)) << 4);                          \
    int aB1 = (rbf1 << 7) | ((lhi ^ (rbf1 & 7)) << 4);                          \
    for (int kt = 0; kt < NT; ++kt) {                                           \
      if (kt < NT - 1) {                                                        \
        asm volatile("s_waitcnt vmcnt(4)\n\ts_barrier" ::: "memory");           \
      } else {                                                                  \
        asm volatile("s_waitcnt vmcnt(0)\n\ts_barrier" ::: "memory");           \
      }                                                                         \
      if (kt + 2 < NT) {                                                        \
        int k0 = (kt + 2) * 64;                                                 \
        gload16(ap0 + k0, la0 + wr2); gload16(ap1 + k0, la1 + wr2);             \
        gload16(bp0 + k0, lb0 + wr2); gload16(bp1 + k0, lb1 + wr2);             \
      }                                                                         \
      const char* ab = (const char*)As + rd;                                    \
      const char* bb = (const char*)Bs + rd;                                    \
      _Pragma("unroll")                                                         \
      for (int ks = 0; ks < 2; ++ks) {                                          \
        int kx = ks << 6;                                                       \
        s16x8 af0 = *(const s16x8*)(ab + (aA0 ^ kx));                           \
        s16x8 af1 = *(const s16x8*)(ab + (aA1 ^ kx));                           \
        s16x8 bf0 = *(const s16x8*)(bb + (aB0 ^ kx));                           \
        s16x8 bf1 = *(const s16x8*)(bb + (aB1 ^ kx));                           \
        ACC[0][0] = __builtin_amdgcn_mfma_f32_16x16x32_bf16(af0, bf0, ACC[0][0], 0, 0, 0); \
        ACC[0][1] = __builtin_amdgcn_mfma_f32_16x16x32_bf16(af0, bf1, ACC[0][1], 0, 0, 0); \
        ACC[1][0] = __builtin_amdgcn_mfma_f32_16x16x32_bf16(af1, bf0, ACC[1][0], 0, 0, 0); \
        ACC[1][1] = __builtin_amdgcn_mfma_f32_16x16x32_bf16(af1, bf1, ACC[1][1], 0, 0, 0); \
      }                                                                         \
      rd = (rd == 16384) ? 0 : rd + 8192;                                       \
      wr2 = (wr2 == 16384) ? 0 : wr2 + 8192;                                    \
    }                                                                           \
  }

// Fused step. blockIdx.y: [0,16) e-GEMM, [16,20) i-GEMM, [20,28) noise for t+1.
__global__ __launch_bounds__(256) void step_kernel(
    const float* __restrict__ re_in, const unsigned short* __restrict__ reb_in,
    const float* __restrict__ ri_in, const unsigned short* __restrict__ rib_in,
    const unsigned short* __restrict__ W_EEb, const unsigned short* __restrict__ W_IET,
    const unsigned short* __restrict__ W_EIT,
    const float* __restrict__ ext,
    const float* __restrict__ sc_gee, const float* __restrict__ sc_gei,
    const float* __restrict__ sc_gie, const float* __restrict__ sc_gin,
    const float* __restrict__ sc_rate_e, const float* __restrict__ sc_rate_i,
    const uint8_t* __restrict__ nz_e_in, const uint8_t* __restrict__ nz_i_in,
    uint8_t* __restrict__ nz_e_out, uint8_t* __restrict__ nz_i_out,
    const U2* __restrict__ subk_e_next, const U2* __restrict__ subk_i_next,
    float* __restrict__ re_out, unsigned short* __restrict__ reb_out,
    float* __restrict__ ri_out, unsigned short* __restrict__ rib_out) {
  __shared__ __align__(16) short As[3 * 4096];   // 3 bufs x 64x64 bf16, swizzled
  __shared__ __align__(16) short Bs[3 * 4096];
  int tid = threadIdx.x;

  if (blockIdx.y >= 20) {                        // noise role: step t+1 k-counts
    if (nz_e_out != nullptr) {
      int flat = ((blockIdx.y - 20) * gridDim.x + blockIdx.x) * 256 + tid;
      gen_noise(flat, NZ_SLICES * 32 * 256, subk_e_next, subk_i_next,
                *sc_rate_e, *sc_rate_i, nz_e_out, nz_i_out);
    }
    return;
  }

  int lane = tid & 63;
  int wave = tid >> 6;
  int wr = wave >> 1, wc = wave & 1;
  int l16 = lane & 15, lhi = lane >> 4;
  int b0 = blockIdx.x * 64;
  bool is_e = blockIdx.y < 16;
  int i0 = (is_e ? blockIdx.y : (blockIdx.y - 16)) * 64;

  f32x4 acc[2][2] = {};
  f32x4 acc2[2][2] = {};

  if (is_e) {
    PIPE_GEMM(reb_in, N_EXC, b0, W_EEb, N_EXC, i0, N_EXC, acc);       // NT=16
    if (rib_in != nullptr) {
      __syncthreads();   // all waves done reading bufs before phase-2 prologue
      PIPE_GEMM(rib_in, N_INH, b0, W_IET, N_INH, i0, N_INH, acc2);    // NT=4
    }
    float gee = *sc_gee, gie = *sc_gie, gin = *sc_gin, rate = *sc_rate_e;
#pragma unroll
    for (int mm = 0; mm < 2; ++mm)
#pragma unroll
      for (int nn = 0; nn < 2; ++nn)
#pragma unroll
        for (int q = 0; q < 4; ++q) {
          int row = b0 + wr * 32 + mm * 16 + lhi * 4 + q;   // C/D: row=(lane>>4)*4+reg
          int col = i0 + wc * 32 + nn * 16 + l16;           //      col=lane&15
          int idx = row * N_EXC + col;
          float val = gee * acc[mm][nn][q] - gie * acc2[mm][nn][q] + gin * ext[idx];
          val += (float)nz_e_in[idx] - rate;
          float ro = re_in[idx];
          float rn = ro + (0.1f * (fmaxf(val, 0.0f) - ro)) / 10.0f;
          rn = fmaxf(rn, 0.0f);
          re_out[idx] = rn;
          reb_out[idx] = f2b(rn);
        }
  } else {
    PIPE_GEMM(reb_in, N_EXC, b0, W_EIT, N_EXC, i0, N_EXC, acc);       // NT=16
    float gei = *sc_gei, rate = *sc_rate_i;
#pragma unroll
    for (int mm = 0; mm < 2; ++mm)
#pragma unroll
      for (int nn = 0; nn < 2; ++nn)
#pragma unroll
        for (int q = 0; q < 4; ++q) {
          int row = b0 + wr * 32 + mm * 16 + lhi * 4 + q;
          int col = i0 + wc * 32 + nn * 16 + l16;
          int idx = row * N_INH + col;
          float val = gei * acc[mm][nn][q];
          val += (float)nz_i_in[idx] - rate;
          float rio = (ri_in != nullptr) ? ri_in[idx] : 0.0f;
          float rn = rio + (0.1f * (fmaxf(val, 0.0f) - rio)) / 5.0f;
          rn = fmaxf(rn, 0.0f);
          ri_out[idx] = rn;
          rib_out[idx] = f2b(rn);
        }
  }
}

extern "C" void kernel_launch(void* const* d_in, const int* in_sizes, int n_in,
                              void* d_out, int out_size, void* d_ws, size_t ws_size,
                              hipStream_t stream) {
  const float* ext    = (const float*)d_in[0];
  const float* h      = (const float*)d_in[1];
  const float* sigma  = (const float*)d_in[2];
  const float* W_EI   = (const float*)d_in[3];
  const float* W_IE   = (const float*)d_in[4];
  const float* g_ee   = (const float*)d_in[5];
  const float* g_ei   = (const float*)d_in[6];
  const float* g_ie   = (const float*)d_in[7];
  const float* g_in   = (const float*)d_in[8];
  const float* rate_e = (const float*)d_in[9];
  const float* rate_i = (const float*)d_in[10];

  char* ws = (char*)d_ws;
  unsigned short* W_EEb = (unsigned short*)ws; ws += (size_t)N_EXC * N_EXC * 2;   // 2 MiB
  unsigned short* W_EIT = (unsigned short*)ws; ws += (size_t)N_INH * N_EXC * 2;   // 0.5
  unsigned short* W_IET = (unsigned short*)ws; ws += (size_t)N_EXC * N_INH * 2;   // 0.5
  float* reA            = (float*)ws;          ws += (size_t)BATCH * N_EXC * 4;   // 8
  unsigned short* rebA  = (unsigned short*)ws; ws += (size_t)BATCH * N_EXC * 2;   // 4
  unsigned short* rebB  = (unsigned short*)ws; ws += (size_t)BATCH * N_EXC * 2;   // 4 (=hb)
  float* riA            = (float*)ws;          ws += (size_t)BATCH * N_INH * 4;   // 2
  float* riB            = (float*)ws;          ws += (size_t)BATCH * N_INH * 4;   // 2
  unsigned short* ribA  = (unsigned short*)ws; ws += (size_t)BATCH * N_INH * 2;   // 1
  unsigned short* ribB  = (unsigned short*)ws; ws += (size_t)BATCH * N_INH * 2;   // 1
  uint8_t* nzE0         = (uint8_t*)ws;        ws += (size_t)NE_TOT;              // 2
  uint8_t* nzE1         = (uint8_t*)ws;        ws += (size_t)NE_TOT;              // 2
  uint8_t* nzI0         = (uint8_t*)ws;        ws += (size_t)BATCH * N_INH;       // 0.5
  uint8_t* nzI1         = (uint8_t*)ws;        ws += (size_t)BATCH * N_INH;       // 0.5
  U2* subk_e            = (U2*)ws;             ws += (size_t)STEPS * MAX_POIS * sizeof(U2);
  U2* subk_i            = (U2*)ws;             ws += (size_t)STEPS * MAX_POIS * sizeof(U2);
  float* re_dout = (float*)d_out;

  wee_kernel<<<dim3(N_EXC), dim3(256), 0, stream>>>(sigma, W_EEb);
  setup_kernel<<<dim3(512), dim3(256), 0, stream>>>(W_EI, W_IE, h, W_EIT, W_IET, rebB);
  keys_kernel<<<dim3(1), dim3(64), 0, stream>>>(subk_e, subk_i);
  noise0_kernel<<<dim3(512), dim3(256), 0, stream>>>(subk_e, subk_i, rate_e, rate_i,
                                                     nzE0, nzI0);

  for (int t = 0; t < STEPS; ++t) {
    const float* re_in          = (t == 0) ? h : ((t & 1) ? reA : re_dout);
    float* re_out               = (t & 1) ? re_dout : reA;
    const unsigned short* rb_in = (t & 1) ? rebA : rebB;   // t=0: rebB holds bf16(h)
    unsigned short* rb_out      = (t & 1) ? rebB : rebA;
    const float* ri_in          = (t == 0) ? nullptr : ((t & 1) ? riA : riB);
    float* ri_out               = (t & 1) ? riB : riA;
    const unsigned short* ib_in = (t == 0) ? nullptr : ((t & 1) ? ribA : ribB);
    unsigned short* ib_out      = (t & 1) ? ribB : ribA;
    const uint8_t* nze_in       = (t & 1) ? nzE1 : nzE0;
    const uint8_t* nzi_in       = (t & 1) ? nzI1 : nzI0;
    uint8_t* nze_out            = (t + 1 < STEPS) ? ((t & 1) ? nzE0 : nzE1) : nullptr;
    uint8_t* nzi_out            = (t + 1 < STEPS) ? ((t & 1) ? nzI0 : nzI1) : nullptr;

    step_kernel<<<dim3(BATCH / 64, 20 + NZ_SLICES), dim3(256), 0, stream>>>(
        re_in, rb_in, ri_in, ib_in, W_EEb, W_IET, W_EIT, ext,
        g_ee, g_ei, g_ie, g_in, rate_e, rate_i,
        nze_in, nzi_in, nze_out, nzi_out,
        subk_e + (t + 1) * MAX_POIS, subk_i + (t + 1) * MAX_POIS,
        re_out, rb_out, ri_out, ib_out);
  }
}

// Round 7
// 502.754 us; speedup vs baseline: 1.3326x; 1.3326x over previous
//
#include <hip/hip_runtime.h>
#include <cstdint>

// RingAttractorNetwork: B=2048, N_EXC=1024, N_INH=256, 10 steps.
// Round 7: revert to 2-buffer __syncthreads pipeline (round-6's 3-buf/vmcnt +
// 48KB LDS regressed via occupancy). Keep noise offload (co-scheduled blocks
// compute step t+1's Poisson k-counts). New: 128x128 block tile, BK=32,
// 4 waves x (64x64 out, 4x4 frags) -> ds_read:MFMA = 1:2 (was 1:1), LDS 32KB.
// Accumulator folding: acc *= -gee/gie between e-phases; epilogue -gie*acc.

#define N_EXC 1024
#define N_INH 256
#define BATCH 2048
#define STEPS 10
#define MAX_POIS 32
#define NE_TOT (BATCH * N_EXC)
#define NTOT   (NE_TOT + BATCH * N_INH)
#define NZ_SLICES 16                      // noise y-slices (x16 blocks = 256)

typedef short s16x8 __attribute__((ext_vector_type(8)));
typedef float f32x4 __attribute__((ext_vector_type(4)));

typedef __attribute__((address_space(1))) const void GV;
typedef __attribute__((address_space(3))) void LV;

struct U2 { uint32_t x, y; };

__device__ __forceinline__ uint32_t rotl32(uint32_t v, int r) {
  return (v << r) | (v >> (32 - r));
}

// JAX threefry2x32 (20 rounds).
__device__ __forceinline__ U2 threefry(U2 k, uint32_t x0, uint32_t x1) {
  uint32_t ks0 = k.x, ks1 = k.y, ks2 = k.x ^ k.y ^ 0x1BD11BDAu;
  x0 += ks0; x1 += ks1;
#define TF_R4(a,b,c,d) \
  x0 += x1; x1 = rotl32(x1,a); x1 ^= x0; \
  x0 += x1; x1 = rotl32(x1,b); x1 ^= x0; \
  x0 += x1; x1 = rotl32(x1,c); x1 ^= x0; \
  x0 += x1; x1 = rotl32(x1,d); x1 ^= x0;
  TF_R4(13,15,26,6)  x0 += ks1; x1 += ks2 + 1u;
  TF_R4(17,29,16,24) x0 += ks2; x1 += ks0 + 2u;
  TF_R4(13,15,26,6)  x0 += ks0; x1 += ks1 + 3u;
  TF_R4(17,29,16,24) x0 += ks1; x1 += ks2 + 4u;
  TF_R4(13,15,26,6)  x0 += ks2; x1 += ks0 + 5u;
#undef TF_R4
  U2 r; r.x = x0; r.y = x1; return r;
}

__device__ __forceinline__ unsigned short f2b(float f) {
  uint32_t u = __float_as_uint(f);
  return (unsigned short)((u + 0x7FFFu + ((u >> 16) & 1u)) >> 16);  // RNE
}

__device__ __forceinline__ void gload16(const void* g, void* l) {
  __builtin_amdgcn_global_load_lds((GV*)g, (LV*)l, 16, 0, 0);
}

// Knuth Poisson k-count for flat elements [f0::stride) of both pools.
// Partitionable random_bits: bits = h.x ^ h.y, h = threefry(subkey_n, 0, e).
__device__ void gen_noise(int f0, int stride,
                          const U2* __restrict__ ske, const U2* __restrict__ ski,
                          float lam_e, float lam_i,
                          uint8_t* __restrict__ nze, uint8_t* __restrict__ nzi) {
  for (int f = f0; f < NTOT; f += stride) {
    bool ii = f >= NE_TOT;
    uint32_t e = ii ? (uint32_t)(f - NE_TOT) : (uint32_t)f;
    const U2* sk = ii ? ski : ske;
    float neg = ii ? -lam_i : -lam_e;
    float lp = 0.0f;
    int k = 0;
#pragma unroll 1
    for (int n = 0; n < MAX_POIS; ++n) {
      if (!(lp > neg)) break;
      k++;
      U2 h = threefry(sk[n], 0u, e);
      uint32_t bits = h.x ^ h.y;
      float u = __uint_as_float((bits >> 9) | 0x3f800000u) - 1.0f;
      lp += logf(u);
    }
    (ii ? nzi : nze)[e] = (uint8_t)(k - 1);
  }
}

// Subkey chains: key = fold_in(key(42), t), split -> (ke, ki); iterated
// fold-like splits give the per-while-iteration uniform subkeys.
__global__ void keys_kernel(U2* subk_e, U2* subk_i) {
  int tid = threadIdx.x;
  if (tid >= 2 * STEPS) return;
  int t = tid >> 1;
  bool is_i = tid & 1;
  U2 base; base.x = 0u; base.y = 42u;
  U2 folded = threefry(base, 0u, (uint32_t)t);        // fold_in
  U2 ke = threefry(folded, 0u, 0u);                   // partitionable split
  U2 ki = threefry(folded, 0u, 1u);
  U2 rng = is_i ? ki : ke;
  U2* dst = (is_i ? subk_i : subk_e) + t * MAX_POIS;
  for (int n = 0; n < MAX_POIS; ++n) {
    dst[n] = threefry(rng, 0u, 1u);                   // subkey
    rng = threefry(rng, 0u, 0u);                      // carried rng
  }
}

// Step-0 noise (once, before the loop).
__global__ __launch_bounds__(256) void noise0_kernel(
    const U2* __restrict__ subk_e, const U2* __restrict__ subk_i,
    const float* __restrict__ sc_rate_e, const float* __restrict__ sc_rate_i,
    uint8_t* __restrict__ nze, uint8_t* __restrict__ nzi) {
  int flat = blockIdx.x * 256 + threadIdx.x;
  gen_noise(flat, gridDim.x * 256, subk_e, subk_i, *sc_rate_e, *sc_rate_i, nze, nzi);
}

// W_EE ring weights -> bf16. Row-normalize (incl. diagonal) in f32, then zero diag.
__global__ __launch_bounds__(256) void wee_kernel(const float* __restrict__ sigma_p,
                                                  unsigned short* __restrict__ W) {
  int i = blockIdx.x;
  int tid = threadIdx.x;
  float sigma = *sigma_p;
  const float twopi = 6.28318530717958647692f;
  const float delta = twopi / 1023.0f;
  float ai = (float)i * delta;
  float w[4];
  float s = 0.0f;
#pragma unroll
  for (int q = 0; q < 4; ++q) {
    int j = tid + q * 256;
    float aj = (float)j * delta;
    float d = aj - ai;
    float wd = atan2f(sinf(d), cosf(d));
    float x = wd / sigma;
    float v = expf(-0.5f * x * x);
    w[q] = v;
    s += v;
  }
  __shared__ float red[256];
  red[tid] = s;
  __syncthreads();
  for (int off = 128; off > 0; off >>= 1) {
    if (tid < off) red[tid] += red[tid + off];
    __syncthreads();
  }
  float sum = red[0];
#pragma unroll
  for (int q = 0; q < 4; ++q) {
    int j = tid + q * 256;
    W[i * N_EXC + j] = (j == i) ? (unsigned short)0 : f2b(w[q] / sum);
  }
}

// Transposed/converted weights + h->bf16.
__global__ void setup_kernel(const float* __restrict__ W_EI, const float* __restrict__ W_IE,
                             const float* __restrict__ h,
                             unsigned short* __restrict__ W_EIT,   // [256][1024]
                             unsigned short* __restrict__ W_IET,   // [1024][256]
                             unsigned short* __restrict__ hb) {
  int tid = blockIdx.x * blockDim.x + threadIdx.x;
  int nt = gridDim.x * blockDim.x;
  for (int i = tid; i < BATCH * N_EXC; i += nt) hb[i] = f2b(h[i]);
  for (int i = tid; i < N_INH * N_EXC; i += nt) {
    int r = i >> 10, c = i & 1023;
    W_EIT[i] = f2b(W_EI[c * N_INH + r]);
  }
  for (int i = tid; i < N_EXC * N_INH; i += nt) {
    int r = i >> 8, c = i & 255;
    W_IET[i] = f2b(W_IE[c * N_EXC + r]);
  }
}

// 128x128-tile GEMM phase, BK=32, 2 LDS bufs, __syncthreads pipeline.
// Tile = 128 rows x 32 k bf16 = 8KB = 512x16B chunks; thread stages chunks
// {tid, tid+256}. Chunk j holds global (row=j>>2, c4=(j&3)^(row&3)) — XOR
// swizzle on the global SOURCE (LDS dest linear, rule 21); read of logical
// (row, c4) -> byte row*64 + ((c4^(row&3))<<4). Loop: [sync; prefetch next
// ->buf^1; compute cur]. Each wave: 4x4 16x16 frags (64x64 out), 8 ds_read
// -> 16 MFMA per tile.
#define PIPE_GEMM(APTR, LDA, AROW0, BPTR, LDB, BROW0, KLEN, ACC)                \
  {                                                                             \
    const int NT = (KLEN) / 32;                                                 \
    int j1 = tid + 256;                                                         \
    int ra0 = tid >> 2, ca0 = ((tid & 3) ^ (ra0 & 3)) << 3;                     \
    int ra1 = j1 >> 2, ca1 = ((j1 & 3) ^ (ra1 & 3)) << 3;                       \
    const unsigned short* ap0 = (APTR) + (size_t)((AROW0) + ra0) * (LDA) + ca0; \
    const unsigned short* ap1 = (APTR) + (size_t)((AROW0) + ra1) * (LDA) + ca1; \
    const unsigned short* bp0 = (BPTR) + (size_t)((BROW0) + ra0) * (LDB) + ca0; \
    const unsigned short* bp1 = (BPTR) + (size_t)((BROW0) + ra1) * (LDB) + ca1; \
    char* la = (char*)As + tid * 16;                                            \
    char* lb = (char*)Bs + tid * 16;                                            \
    gload16(ap0, la); gload16(ap1, la + 4096);                                  \
    gload16(bp0, lb); gload16(bp1, lb + 4096);                                  \
    int cur = 0;                                                                \
    for (int kt = 0; kt < NT; ++kt) {                                           \
      __syncthreads();                                                          \
      if (kt + 1 < NT) {                                                        \
        int k0 = (kt + 1) * 32;                                                 \
        int nb = (cur ^ 1) * 8192;                                              \
        gload16(ap0 + k0, la + nb); gload16(ap1 + k0, la + nb + 4096);          \
        gload16(bp0 + k0, lb + nb); gload16(bp1 + k0, lb + nb + 4096);          \
      }                                                                         \
      const char* ab = (const char*)As + cur * 8192;                            \
      const char* bb = (const char*)Bs + cur * 8192;                            \
      s16x8 af[4], bf[4];                                                       \
      _Pragma("unroll")                                                         \
      for (int m = 0; m < 4; ++m) {                                             \
        int rA = wr * 64 + m * 16 + l16;                                        \
        int rB = wc * 64 + m * 16 + l16;                                        \
        int sw = (lhi ^ (l16 & 3)) << 4;                                        \
        af[m] = *(const s16x8*)(ab + rA * 64 + sw);                             \
        bf[m] = *(const s16x8*)(bb + rB * 64 + sw);                             \
      }                                                                         \
      _Pragma("unroll")                                                         \
      for (int m = 0; m < 4; ++m)                                               \
        _Pragma("unroll")                                                       \
        for (int n = 0; n < 4; ++n)                                             \
          ACC[m][n] = __builtin_amdgcn_mfma_f32_16x16x32_bf16(af[m], bf[n], ACC[m][n], 0, 0, 0); \
      cur ^= 1;                                                                 \
    }                                                                           \
  }

// Fused step. blockIdx.y: [0,8) e-GEMM cols, [8,10) i-GEMM cols, [10,26) noise t+1.
__global__ __launch_bounds__(256) void step_kernel(
    const float* __restrict__ re_in, const unsigned short* __restrict__ reb_in,
    const float* __restrict__ ri_in, const unsigned short* __restrict__ rib_in,
    const unsigned short* __restrict__ W_EEb, const unsigned short* __restrict__ W_IET,
    const unsigned short* __restrict__ W_EIT,
    const float* __restrict__ ext,
    const float* __restrict__ sc_gee, const float* __restrict__ sc_gei,
    const float* __restrict__ sc_gie, const float* __restrict__ sc_gin,
    const float* __restrict__ sc_rate_e, const float* __restrict__ sc_rate_i,
    const uint8_t* __restrict__ nz_e_in, const uint8_t* __restrict__ nz_i_in,
    uint8_t* __restrict__ nz_e_out, uint8_t* __restrict__ nz_i_out,
    const U2* __restrict__ subk_e_next, const U2* __restrict__ subk_i_next,
    float* __restrict__ re_out, unsigned short* __restrict__ reb_out,
    float* __restrict__ ri_out, unsigned short* __restrict__ rib_out) {
  __shared__ __align__(16) short As[2 * 4096];   // 2 bufs x 128x32 bf16 (8KB each)
  __shared__ __align__(16) short Bs[2 * 4096];
  int tid = threadIdx.x;

  if (blockIdx.y >= 10) {                        // noise role: step t+1 k-counts
    if (nz_e_out != nullptr) {
      int flat = ((blockIdx.y - 10) * gridDim.x + blockIdx.x) * 256 + tid;
      gen_noise(flat, NZ_SLICES * 16 * 256, subk_e_next, subk_i_next,
                *sc_rate_e, *sc_rate_i, nz_e_out, nz_i_out);
    }
    return;
  }

  int lane = tid & 63;
  int wave = tid >> 6;
  int wr = wave >> 1, wc = wave & 1;               // wave -> 64x64 quadrant
  int l16 = lane & 15, lhi = lane >> 4;
  int b0 = blockIdx.x * 128;
  bool is_e = blockIdx.y < 8;
  int i0 = (is_e ? blockIdx.y : (blockIdx.y - 8)) * 128;

  f32x4 acc[4][4] = {};

  if (is_e) {
    PIPE_GEMM(reb_in, N_EXC, b0, W_EEb, N_EXC, i0, N_EXC, acc);        // NT=32
    float gee = *sc_gee, gie = *sc_gie, gin = *sc_gin, rate = *sc_rate_e;
    bool has_i = (rib_in != nullptr);
    if (has_i) {
      // Fold: want gee*S1 - gie*S2.  acc = S1 -> acc *= -gee/gie; then
      // accumulate S2 via MFMA; epilogue multiplies by -gie. (gie = 2.0 here.)
      float sc = -gee / gie;
#pragma unroll
      for (int m = 0; m < 4; ++m)
#pragma unroll
        for (int n = 0; n < 4; ++n)
#pragma unroll
          for (int q = 0; q < 4; ++q) acc[m][n][q] *= sc;
      __syncthreads();   // all waves done with bufs before phase-2 prologue
      PIPE_GEMM(rib_in, N_INH, b0, W_IET, N_INH, i0, N_INH, acc);      // NT=8
    }
    float mul = has_i ? -gie : gee;
#pragma unroll
    for (int mm = 0; mm < 4; ++mm)
#pragma unroll
      for (int nn = 0; nn < 4; ++nn)
#pragma unroll
        for (int q = 0; q < 4; ++q) {
          int row = b0 + wr * 64 + mm * 16 + lhi * 4 + q;   // C/D: row=(lane>>4)*4+reg
          int col = i0 + wc * 64 + nn * 16 + l16;           //      col=lane&15
          int idx = row * N_EXC + col;
          float val = mul * acc[mm][nn][q] + gin * ext[idx];
          val += (float)nz_e_in[idx] - rate;
          float ro = re_in[idx];
          float rn = ro + (0.1f * (fmaxf(val, 0.0f) - ro)) / 10.0f;
          rn = fmaxf(rn, 0.0f);
          re_out[idx] = rn;
          reb_out[idx] = f2b(rn);
        }
  } else {
    PIPE_GEMM(reb_in, N_EXC, b0, W_EIT, N_EXC, i0, N_EXC, acc);        // NT=32
    float gei = *sc_gei, rate = *sc_rate_i;
#pragma unroll
    for (int mm = 0; mm < 4; ++mm)
#pragma unroll
      for (int nn = 0; nn < 4; ++nn)
#pragma unroll
        for (int q = 0; q < 4; ++q) {
          int row = b0 + wr * 64 + mm * 16 + lhi * 4 + q;
          int col = i0 + wc * 64 + nn * 16 + l16;
          int idx = row * N_INH + col;
          float val = gei * acc[mm][nn][q];
          val += (float)nz_i_in[idx] - rate;
          float rio = (ri_in != nullptr) ? ri_in[idx] : 0.0f;
          float rn = rio + (0.1f * (fmaxf(val, 0.0f) - rio)) / 5.0f;
          rn = fmaxf(rn, 0.0f);
          ri_out[idx] = rn;
          rib_out[idx] = f2b(rn);
        }
  }
}

extern "C" void kernel_launch(void* const* d_in, const int* in_sizes, int n_in,
                              void* d_out, int out_size, void* d_ws, size_t ws_size,
                              hipStream_t stream) {
  const float* ext    = (const float*)d_in[0];
  const float* h      = (const float*)d_in[1];
  const float* sigma  = (const float*)d_in[2];
  const float* W_EI   = (const float*)d_in[3];
  const float* W_IE   = (const float*)d_in[4];
  const float* g_ee   = (const float*)d_in[5];
  const float* g_ei   = (const float*)d_in[6];
  const float* g_ie   = (const float*)d_in[7];
  const float* g_in   = (const float*)d_in[8];
  const float* rate_e = (const float*)d_in[9];
  const float* rate_i = (const float*)d_in[10];

  char* ws = (char*)d_ws;
  unsigned short* W_EEb = (unsigned short*)ws; ws += (size_t)N_EXC * N_EXC * 2;
  unsigned short* W_EIT = (unsigned short*)ws; ws += (size_t)N_INH * N_EXC * 2;
  unsigned short* W_IET = (unsigned short*)ws; ws += (size_t)N_EXC * N_INH * 2;
  float* reA            = (float*)ws;          ws += (size_t)BATCH * N_EXC * 4;
  unsigned short* rebA  = (unsigned short*)ws; ws += (size_t)BATCH * N_EXC * 2;
  unsigned short* rebB  = (unsigned short*)ws; ws += (size_t)BATCH * N_EXC * 2;
  float* riA            = (float*)ws;          ws += (size_t)BATCH * N_INH * 4;
  float* riB            = (float*)ws;          ws += (size_t)BATCH * N_INH * 4;
  unsigned short* ribA  = (unsigned short*)ws; ws += (size_t)BATCH * N_INH * 2;
  unsigned short* ribB  = (unsigned short*)ws; ws += (size_t)BATCH * N_INH * 2;
  uint8_t* nzE0         = (uint8_t*)ws;        ws += (size_t)NE_TOT;
  uint8_t* nzE1         = (uint8_t*)ws;        ws += (size_t)NE_TOT;
  uint8_t* nzI0         = (uint8_t*)ws;        ws += (size_t)BATCH * N_INH;
  uint8_t* nzI1         = (uint8_t*)ws;        ws += (size_t)BATCH * N_INH;
  U2* subk_e            = (U2*)ws;             ws += (size_t)STEPS * MAX_POIS * sizeof(U2);
  U2* subk_i            = (U2*)ws;             ws += (size_t)STEPS * MAX_POIS * sizeof(U2);
  float* re_dout = (float*)d_out;

  wee_kernel<<<dim3(N_EXC), dim3(256), 0, stream>>>(sigma, W_EEb);
  setup_kernel<<<dim3(512), dim3(256), 0, stream>>>(W_EI, W_IE, h, W_EIT, W_IET, rebB);
  keys_kernel<<<dim3(1), dim3(64), 0, stream>>>(subk_e, subk_i);
  noise0_kernel<<<dim3(512), dim3(256), 0, stream>>>(subk_e, subk_i, rate_e, rate_i,
                                                     nzE0, nzI0);

  for (int t = 0; t < STEPS; ++t) {
    const float* re_in          = (t == 0) ? h : ((t & 1) ? reA : re_dout);
    float* re_out               = (t & 1) ? re_dout : reA;
    const unsigned short* rb_in = (t & 1) ? rebA : rebB;   // t=0: rebB holds bf16(h)
    unsigned short* rb_out      = (t & 1) ? rebB : rebA;
    const float* ri_in          = (t == 0) ? nullptr : ((t & 1) ? riA : riB);
    float* ri_out               = (t & 1) ? riB : riA;
    const unsigned short* ib_in = (t == 0) ? nullptr : ((t & 1) ? ribA : ribB);
    unsigned short* ib_out      = (t & 1) ? ribB : ribA;
    const uint8_t* nze_in       = (t & 1) ? nzE1 : nzE0;
    const uint8_t* nzi_in       = (t & 1) ? nzI1 : nzI0;
    uint8_t* nze_out            = (t + 1 < STEPS) ? ((t & 1) ? nzE0 : nzE1) : nullptr;
    uint8_t* nzi_out            = (t + 1 < STEPS) ? ((t & 1) ? nzI0 : nzI1) : nullptr;

    step_kernel<<<dim3(BATCH / 128, 10 + NZ_SLICES), dim3(256), 0, stream>>>(
        re_in, rb_in, ri_in, ib_in, W_EEb, W_IET, W_EIT, ext,
        g_ee, g_ei, g_ie, g_in, rate_e, rate_i,
        nze_in, nzi_in, nze_out, nzi_out,
        subk_e + (t + 1) * MAX_POIS, subk_i + (t + 1) * MAX_POIS,
        re_out, rb_out, ri_out, ib_out);
  }
}

// Round 8
// 443.925 us; speedup vs baseline: 1.5092x; 1.1325x over previous
//
#include <hip/hip_runtime.h>
#include <cstdint>

// RingAttractorNetwork: B=2048, N_EXC=1024, N_INH=256, 10 steps.
// Round 8: round-5 GEMM structure EXACTLY (64x64 tiles, BK=64, conflict-free
// 8-slot XOR swizzle, 2-buf barrier-first pipeline, 640 GEMM blocks) + noise
// offload from r6/r7 (co-scheduled blocks compute step t+1's Poisson k-counts;
// epilogue reads u8). Single-variable change vs round 5.

#define N_EXC 1024
#define N_INH 256
#define BATCH 2048
#define STEPS 10
#define MAX_POIS 32
#define NE_TOT (BATCH * N_EXC)
#define NTOT   (NE_TOT + BATCH * N_INH)
#define NZ_SLICES 8                       // noise y-slices (x32 blocks = 256)

typedef short s16x8 __attribute__((ext_vector_type(8)));
typedef float f32x4 __attribute__((ext_vector_type(4)));

typedef __attribute__((address_space(1))) const void GV;
typedef __attribute__((address_space(3))) void LV;

struct U2 { uint32_t x, y; };

__device__ __forceinline__ uint32_t rotl32(uint32_t v, int r) {
  return (v << r) | (v >> (32 - r));
}

// JAX threefry2x32 (20 rounds).
__device__ __forceinline__ U2 threefry(U2 k, uint32_t x0, uint32_t x1) {
  uint32_t ks0 = k.x, ks1 = k.y, ks2 = k.x ^ k.y ^ 0x1BD11BDAu;
  x0 += ks0; x1 += ks1;
#define TF_R4(a,b,c,d) \
  x0 += x1; x1 = rotl32(x1,a); x1 ^= x0; \
  x0 += x1; x1 = rotl32(x1,b); x1 ^= x0; \
  x0 += x1; x1 = rotl32(x1,c); x1 ^= x0; \
  x0 += x1; x1 = rotl32(x1,d); x1 ^= x0;
  TF_R4(13,15,26,6)  x0 += ks1; x1 += ks2 + 1u;
  TF_R4(17,29,16,24) x0 += ks2; x1 += ks0 + 2u;
  TF_R4(13,15,26,6)  x0 += ks0; x1 += ks1 + 3u;
  TF_R4(17,29,16,24) x0 += ks1; x1 += ks2 + 4u;
  TF_R4(13,15,26,6)  x0 += ks2; x1 += ks0 + 5u;
#undef TF_R4
  U2 r; r.x = x0; r.y = x1; return r;
}

__device__ __forceinline__ unsigned short f2b(float f) {
  uint32_t u = __float_as_uint(f);
  return (unsigned short)((u + 0x7FFFu + ((u >> 16) & 1u)) >> 16);  // RNE
}

__device__ __forceinline__ void gload16(const void* g, void* l) {
  __builtin_amdgcn_global_load_lds((GV*)g, (LV*)l, 16, 0, 0);
}

// Knuth Poisson k-count for flat elements [f0::stride) of both pools.
// Partitionable random_bits: bits = h.x ^ h.y, h = threefry(subkey_n, 0, e).
__device__ void gen_noise(int f0, int stride,
                          const U2* __restrict__ ske, const U2* __restrict__ ski,
                          float lam_e, float lam_i,
                          uint8_t* __restrict__ nze, uint8_t* __restrict__ nzi) {
  for (int f = f0; f < NTOT; f += stride) {
    bool ii = f >= NE_TOT;
    uint32_t e = ii ? (uint32_t)(f - NE_TOT) : (uint32_t)f;
    const U2* sk = ii ? ski : ske;
    float neg = ii ? -lam_i : -lam_e;
    float lp = 0.0f;
    int k = 0;
#pragma unroll 1
    for (int n = 0; n < MAX_POIS; ++n) {
      if (!(lp > neg)) break;
      k++;
      U2 h = threefry(sk[n], 0u, e);
      uint32_t bits = h.x ^ h.y;
      float u = __uint_as_float((bits >> 9) | 0x3f800000u) - 1.0f;
      lp += logf(u);
    }
    (ii ? nzi : nze)[e] = (uint8_t)(k - 1);
  }
}

// Subkey chains: key = fold_in(key(42), t), split -> (ke, ki); iterated
// fold-like splits give the per-while-iteration uniform subkeys.
__global__ void keys_kernel(U2* subk_e, U2* subk_i) {
  int tid = threadIdx.x;
  if (tid >= 2 * STEPS) return;
  int t = tid >> 1;
  bool is_i = tid & 1;
  U2 base; base.x = 0u; base.y = 42u;
  U2 folded = threefry(base, 0u, (uint32_t)t);        // fold_in
  U2 ke = threefry(folded, 0u, 0u);                   // partitionable split
  U2 ki = threefry(folded, 0u, 1u);
  U2 rng = is_i ? ki : ke;
  U2* dst = (is_i ? subk_i : subk_e) + t * MAX_POIS;
  for (int n = 0; n < MAX_POIS; ++n) {
    dst[n] = threefry(rng, 0u, 1u);                   // subkey
    rng = threefry(rng, 0u, 0u);                      // carried rng
  }
}

// Step-0 noise (once, before the loop).
__global__ __launch_bounds__(256) void noise0_kernel(
    const U2* __restrict__ subk_e, const U2* __restrict__ subk_i,
    const float* __restrict__ sc_rate_e, const float* __restrict__ sc_rate_i,
    uint8_t* __restrict__ nze, uint8_t* __restrict__ nzi) {
  int flat = blockIdx.x * 256 + threadIdx.x;
  gen_noise(flat, gridDim.x * 256, subk_e, subk_i, *sc_rate_e, *sc_rate_i, nze, nzi);
}

// W_EE ring weights -> bf16. Row-normalize (incl. diagonal) in f32, then zero diag.
__global__ __launch_bounds__(256) void wee_kernel(const float* __restrict__ sigma_p,
                                                  unsigned short* __restrict__ W) {
  int i = blockIdx.x;
  int tid = threadIdx.x;
  float sigma = *sigma_p;
  const float twopi = 6.28318530717958647692f;
  const float delta = twopi / 1023.0f;
  float ai = (float)i * delta;
  float w[4];
  float s = 0.0f;
#pragma unroll
  for (int q = 0; q < 4; ++q) {
    int j = tid + q * 256;
    float aj = (float)j * delta;
    float d = aj - ai;
    float wd = atan2f(sinf(d), cosf(d));
    float x = wd / sigma;
    float v = expf(-0.5f * x * x);
    w[q] = v;
    s += v;
  }
  __shared__ float red[256];
  red[tid] = s;
  __syncthreads();
  for (int off = 128; off > 0; off >>= 1) {
    if (tid < off) red[tid] += red[tid + off];
    __syncthreads();
  }
  float sum = red[0];
#pragma unroll
  for (int q = 0; q < 4; ++q) {
    int j = tid + q * 256;
    W[i * N_EXC + j] = (j == i) ? (unsigned short)0 : f2b(w[q] / sum);
  }
}

// Transposed/converted weights + h->bf16.
__global__ void setup_kernel(const float* __restrict__ W_EI, const float* __restrict__ W_IE,
                             const float* __restrict__ h,
                             unsigned short* __restrict__ W_EIT,   // [256][1024]
                             unsigned short* __restrict__ W_IET,   // [1024][256]
                             unsigned short* __restrict__ hb) {
  int tid = blockIdx.x * blockDim.x + threadIdx.x;
  int nt = gridDim.x * blockDim.x;
  for (int i = tid; i < BATCH * N_EXC; i += nt) hb[i] = f2b(h[i]);
  for (int i = tid; i < N_INH * N_EXC; i += nt) {
    int r = i >> 10, c = i & 1023;
    W_EIT[i] = f2b(W_EI[c * N_INH + r]);
  }
  for (int i = tid; i < N_EXC * N_INH; i += nt) {
    int r = i >> 8, c = i & 255;
    W_IET[i] = f2b(W_IE[c * N_EXC + r]);
  }
}

// Pipelined 64x64-tile GEMM phase, double-buffered, gload_lds-staged, XOR-swizzled.
// LDS chunk j (16B) of a [64][64]-bf16 tile holds global (row=j>>3, col16=(j&7)^(row&7)).
// Read of logical (r,c16) -> byte (r<<7) | ((c16^(r&7))<<4). Swizzle on BOTH the
// global source and the ds_read (rule 21). 8-slot spread = 0 measured conflicts (r6).
// Loop: [__syncthreads; prefetch T(kt+1)->buf^1; compute T(kt)] — barrier's
// vmcnt(0) drains the prefetch issued one full tile earlier.
#define PIPE_GEMM(APTR, LDA, AROW0, BPTR, LDB, BROW0, KLEN, ACC)                \
  {                                                                             \
    const int NT = (KLEN) / 64;                                                 \
    int c0 = wave * 128 + lane;                                                 \
    int c1 = c0 + 64;                                                           \
    int r0 = c0 >> 3, q0 = ((c0 & 7) ^ (r0 & 7)) << 3;                          \
    int r1 = c1 >> 3, q1 = ((c1 & 7) ^ (r1 & 7)) << 3;                          \
    const unsigned short* ap0 = (APTR) + (size_t)((AROW0) + r0) * (LDA) + q0;   \
    const unsigned short* ap1 = (APTR) + (size_t)((AROW0) + r1) * (LDA) + q1;   \
    const unsigned short* bp0 = (BPTR) + (size_t)((BROW0) + r0) * (LDB) + q0;   \
    const unsigned short* bp1 = (BPTR) + (size_t)((BROW0) + r1) * (LDB) + q1;   \
    char* la0 = (char*)As + wave * 2048;                                        \
    char* la1 = la0 + 1024;                                                     \
    char* lb0 = (char*)Bs + wave * 2048;                                        \
    char* lb1 = lb0 + 1024;                                                     \
    gload16(ap0, la0); gload16(ap1, la1);                                       \
    gload16(bp0, lb0); gload16(bp1, lb1);                                       \
    int cur = 0;                                                                \
    int raf0 = wr * 32 + l16, raf1 = raf0 + 16;                                 \
    int rbf0 = wc * 32 + l16, rbf1 = rbf0 + 16;                                 \
    int aA0 = (raf0 << 7) | ((lhi ^ (raf0 & 7)) << 4);                          \
    int aA1 = (raf1 << 7) | ((lhi ^ (raf1 & 7)) << 4);                          \
    int aB0 = (rbf0 << 7) | ((lhi ^ (rbf0 & 7)) << 4);                          \
    int aB1 = (rbf1 << 7) | ((lhi ^ (rbf1 & 7)) << 4);                          \
    for (int kt = 0; kt < NT; ++kt) {                                           \
      __syncthreads();                                                          \
      if (kt + 1 < NT) {                                                        \
        int k0 = (kt + 1) * 64;                                                 \
        int nb = (cur ^ 1) * 8192;                                              \
        gload16(ap0 + k0, la0 + nb); gload16(ap1 + k0, la1 + nb);               \
        gload16(bp0 + k0, lb0 + nb); gload16(bp1 + k0, lb1 + nb);               \
      }                                                                         \
      const char* ab = (const char*)As + cur * 8192;                            \
      const char* bb = (const char*)Bs + cur * 8192;                            \
      _Pragma("unroll")                                                         \
      for (int ks = 0; ks < 2; ++ks) {                                          \
        int kx = ks << 6;                                                       \
        s16x8 af0 = *(const s16x8*)(ab + (aA0 ^ kx));                           \
        s16x8 af1 = *(const s16x8*)(ab + (aA1 ^ kx));                           \
        s16x8 bf0 = *(const s16x8*)(bb + (aB0 ^ kx));                           \
        s16x8 bf1 = *(const s16x8*)(bb + (aB1 ^ kx));                           \
        ACC[0][0] = __builtin_amdgcn_mfma_f32_16x16x32_bf16(af0, bf0, ACC[0][0], 0, 0, 0); \
        ACC[0][1] = __builtin_amdgcn_mfma_f32_16x16x32_bf16(af0, bf1, ACC[0][1], 0, 0, 0); \
        ACC[1][0] = __builtin_amdgcn_mfma_f32_16x16x32_bf16(af1, bf0, ACC[1][0], 0, 0, 0); \
        ACC[1][1] = __builtin_amdgcn_mfma_f32_16x16x32_bf16(af1, bf1, ACC[1][1], 0, 0, 0); \
      }                                                                         \
      cur ^= 1;                                                                 \
    }                                                                           \
  }

// Fused step. blockIdx.y: [0,16) e-GEMM, [16,20) i-GEMM, [20,28) noise for t+1.
__global__ __launch_bounds__(256) void step_kernel(
    const float* __restrict__ re_in, const unsigned short* __restrict__ reb_in,
    const float* __restrict__ ri_in, const unsigned short* __restrict__ rib_in,
    const unsigned short* __restrict__ W_EEb, const unsigned short* __restrict__ W_IET,
    const unsigned short* __restrict__ W_EIT,
    const float* __restrict__ ext,
    const float* __restrict__ sc_gee, const float* __restrict__ sc_gei,
    const float* __restrict__ sc_gie, const float* __restrict__ sc_gin,
    const float* __restrict__ sc_rate_e, const float* __restrict__ sc_rate_i,
    const uint8_t* __restrict__ nz_e_in, const uint8_t* __restrict__ nz_i_in,
    uint8_t* __restrict__ nz_e_out, uint8_t* __restrict__ nz_i_out,
    const U2* __restrict__ subk_e_next, const U2* __restrict__ subk_i_next,
    float* __restrict__ re_out, unsigned short* __restrict__ reb_out,
    float* __restrict__ ri_out, unsigned short* __restrict__ rib_out) {
  __shared__ __align__(16) short As[2 * 4096];   // 2 bufs x 64x64 bf16, swizzled
  __shared__ __align__(16) short Bs[2 * 4096];
  int tid = threadIdx.x;

  if (blockIdx.y >= 20) {                        // noise role: step t+1 k-counts
    if (nz_e_out != nullptr) {
      int flat = ((blockIdx.y - 20) * gridDim.x + blockIdx.x) * 256 + tid;
      gen_noise(flat, NZ_SLICES * 32 * 256, subk_e_next, subk_i_next,
                *sc_rate_e, *sc_rate_i, nz_e_out, nz_i_out);
    }
    return;
  }

  int lane = tid & 63;
  int wave = tid >> 6;
  int wr = wave >> 1, wc = wave & 1;
  int l16 = lane & 15, lhi = lane >> 4;
  int b0 = blockIdx.x * 64;
  bool is_e = blockIdx.y < 16;
  int i0 = (is_e ? blockIdx.y : (blockIdx.y - 16)) * 64;

  f32x4 acc[2][2] = {};
  f32x4 acc2[2][2] = {};

  if (is_e) {
    PIPE_GEMM(reb_in, N_EXC, b0, W_EEb, N_EXC, i0, N_EXC, acc);       // NT=16
    if (rib_in != nullptr) {
      PIPE_GEMM(rib_in, N_INH, b0, W_IET, N_INH, i0, N_INH, acc2);    // NT=4
    }
    float gee = *sc_gee, gie = *sc_gie, gin = *sc_gin, rate = *sc_rate_e;
#pragma unroll
    for (int mm = 0; mm < 2; ++mm)
#pragma unroll
      for (int nn = 0; nn < 2; ++nn)
#pragma unroll
        for (int q = 0; q < 4; ++q) {
          int row = b0 + wr * 32 + mm * 16 + lhi * 4 + q;   // C/D: row=(lane>>4)*4+reg
          int col = i0 + wc * 32 + nn * 16 + l16;           //      col=lane&15
          int idx = row * N_EXC + col;
          float val = gee * acc[mm][nn][q] - gie * acc2[mm][nn][q] + gin * ext[idx];
          val += (float)nz_e_in[idx] - rate;
          float ro = re_in[idx];
          float rn = ro + (0.1f * (fmaxf(val, 0.0f) - ro)) / 10.0f;
          rn = fmaxf(rn, 0.0f);
          re_out[idx] = rn;
          reb_out[idx] = f2b(rn);
        }
  } else {
    PIPE_GEMM(reb_in, N_EXC, b0, W_EIT, N_EXC, i0, N_EXC, acc);       // NT=16
    float gei = *sc_gei, rate = *sc_rate_i;
#pragma unroll
    for (int mm = 0; mm < 2; ++mm)
#pragma unroll
      for (int nn = 0; nn < 2; ++nn)
#pragma unroll
        for (int q = 0; q < 4; ++q) {
          int row = b0 + wr * 32 + mm * 16 + lhi * 4 + q;
          int col = i0 + wc * 32 + nn * 16 + l16;
          int idx = row * N_INH + col;
          float val = gei * acc[mm][nn][q];
          val += (float)nz_i_in[idx] - rate;
          float rio = (ri_in != nullptr) ? ri_in[idx] : 0.0f;
          float rn = rio + (0.1f * (fmaxf(val, 0.0f) - rio)) / 5.0f;
          rn = fmaxf(rn, 0.0f);
          ri_out[idx] = rn;
          rib_out[idx] = f2b(rn);
        }
  }
}

extern "C" void kernel_launch(void* const* d_in, const int* in_sizes, int n_in,
                              void* d_out, int out_size, void* d_ws, size_t ws_size,
                              hipStream_t stream) {
  const float* ext    = (const float*)d_in[0];
  const float* h      = (const float*)d_in[1];
  const float* sigma  = (const float*)d_in[2];
  const float* W_EI   = (const float*)d_in[3];
  const float* W_IE   = (const float*)d_in[4];
  const float* g_ee   = (const float*)d_in[5];
  const float* g_ei   = (const float*)d_in[6];
  const float* g_ie   = (const float*)d_in[7];
  const float* g_in   = (const float*)d_in[8];
  const float* rate_e = (const float*)d_in[9];
  const float* rate_i = (const float*)d_in[10];

  char* ws = (char*)d_ws;
  unsigned short* W_EEb = (unsigned short*)ws; ws += (size_t)N_EXC * N_EXC * 2;
  unsigned short* W_EIT = (unsigned short*)ws; ws += (size_t)N_INH * N_EXC * 2;
  unsigned short* W_IET = (unsigned short*)ws; ws += (size_t)N_EXC * N_INH * 2;
  float* reA            = (float*)ws;          ws += (size_t)BATCH * N_EXC * 4;
  unsigned short* rebA  = (unsigned short*)ws; ws += (size_t)BATCH * N_EXC * 2;
  unsigned short* rebB  = (unsigned short*)ws; ws += (size_t)BATCH * N_EXC * 2;
  float* riA            = (float*)ws;          ws += (size_t)BATCH * N_INH * 4;
  float* riB            = (float*)ws;          ws += (size_t)BATCH * N_INH * 4;
  unsigned short* ribA  = (unsigned short*)ws; ws += (size_t)BATCH * N_INH * 2;
  unsigned short* ribB  = (unsigned short*)ws; ws += (size_t)BATCH * N_INH * 2;
  uint8_t* nzE0         = (uint8_t*)ws;        ws += (size_t)NE_TOT;
  uint8_t* nzE1         = (uint8_t*)ws;        ws += (size_t)NE_TOT;
  uint8_t* nzI0         = (uint8_t*)ws;        ws += (size_t)BATCH * N_INH;
  uint8_t* nzI1         = (uint8_t*)ws;        ws += (size_t)BATCH * N_INH;
  U2* subk_e            = (U2*)ws;             ws += (size_t)(STEPS + 1) * MAX_POIS * sizeof(U2);
  U2* subk_i            = (U2*)ws;             ws += (size_t)(STEPS + 1) * MAX_POIS * sizeof(U2);
  float* re_dout = (float*)d_out;

  wee_kernel<<<dim3(N_EXC), dim3(256), 0, stream>>>(sigma, W_EEb);
  setup_kernel<<<dim3(512), dim3(256), 0, stream>>>(W_EI, W_IE, h, W_EIT, W_IET, rebB);
  keys_kernel<<<dim3(1), dim3(64), 0, stream>>>(subk_e, subk_i);
  noise0_kernel<<<dim3(512), dim3(256), 0, stream>>>(subk_e, subk_i, rate_e, rate_i,
                                                     nzE0, nzI0);

  for (int t = 0; t < STEPS; ++t) {
    const float* re_in          = (t == 0) ? h : ((t & 1) ? reA : re_dout);
    float* re_out               = (t & 1) ? re_dout : reA;
    const unsigned short* rb_in = (t & 1) ? rebA : rebB;   // t=0: rebB holds bf16(h)
    unsigned short* rb_out      = (t & 1) ? rebB : rebA;
    const float* ri_in          = (t == 0) ? nullptr : ((t & 1) ? riA : riB);
    float* ri_out               = (t & 1) ? riB : riA;
    const unsigned short* ib_in = (t == 0) ? nullptr : ((t & 1) ? ribA : ribB);
    unsigned short* ib_out      = (t & 1) ? ribB : ribA;
    const uint8_t* nze_in       = (t & 1) ? nzE1 : nzE0;
    const uint8_t* nzi_in       = (t & 1) ? nzI1 : nzI0;
    uint8_t* nze_out            = (t + 1 < STEPS) ? ((t & 1) ? nzE0 : nzE1) : nullptr;
    uint8_t* nzi_out            = (t + 1 < STEPS) ? ((t & 1) ? nzI0 : nzI1) : nullptr;

    step_kernel<<<dim3(BATCH / 64, 20 + NZ_SLICES), dim3(256), 0, stream>>>(
        re_in, rb_in, ri_in, ib_in, W_EEb, W_IET, W_EIT, ext,
        g_ee, g_ei, g_ie, g_in, rate_e, rate_i,
        nze_in, nzi_in, nze_out, nzi_out,
        subk_e + (t + 1) * MAX_POIS, subk_i + (t + 1) * MAX_POIS,
        re_out, rb_out, ri_out, ib_out);
  }
}